// Round 1
// baseline (179.039 us; speedup 1.0000x reference)
//
#include <hip/hip_runtime.h>
#include <math.h>

// ExpertRouter: B=8, N=4096, D=1024, E=2  -> rows = 32768
// Outputs (concatenated float32):
//   [0 .. 65535]        expert_weights  [rows,2]  (0/1)
//   [65536 .. 98303]    expert_decisions [rows]   (0/1, "both experts kept")
//   [98304]             gating_loss scalar

constexpr int D = 1024;
constexpr int ROWS = 32768;
constexpr int OUT_DEC = ROWS * 2;   // 65536
constexpr int OUT_LOSS = ROWS * 3;  // 98304

static __device__ __forceinline__ float softplusf(float v) {
    // logaddexp(v, 0) = max(v,0) + log1p(exp(-|v|))  (matches jax.nn.softplus)
    return fmaxf(v, 0.0f) + log1pf(expf(-fabsf(v)));
}

__global__ __launch_bounds__(256) void router_main(
    const float* __restrict__ x,        // [ROWS, D]
    const float* __restrict__ gate_w,   // [2, D]
    const float* __restrict__ noise_w,  // [2, D]
    const float* __restrict__ ns,       // [ROWS, 2]
    float* __restrict__ out,            // [ROWS*3 + 1]
    double* __restrict__ acc)           // [3]: imp0, imp1, ent_sum (pre-zeroed)
{
    const int lane   = threadIdx.x & 63;
    const int gtid   = blockIdx.x * blockDim.x + threadIdx.x;
    const int wave   = gtid >> 6;
    const int nwaves = (gridDim.x * blockDim.x) >> 6;
    const int base   = lane * 16;   // 64 lanes * 16 floats = 1024 = D

    // Per-lane register copy of this lane's 16-element slice of all 4 weight rows.
    float4 wg0[4], wg1[4], wn0[4], wn1[4];
#pragma unroll
    for (int i = 0; i < 4; ++i) {
        wg0[i] = *(const float4*)(gate_w + base + 4 * i);
        wg1[i] = *(const float4*)(gate_w + D + base + 4 * i);
        wn0[i] = *(const float4*)(noise_w + base + 4 * i);
        wn1[i] = *(const float4*)(noise_w + D + base + 4 * i);
    }

    double imp0 = 0.0, imp1 = 0.0, entsum = 0.0;

    for (int row = wave; row < ROWS; row += nwaves) {
        const float* xr = x + (size_t)row * D + base;
        float c0 = 0.f, c1 = 0.f, n0 = 0.f, n1 = 0.f;
#pragma unroll
        for (int i = 0; i < 4; ++i) {
            float4 xv = *(const float4*)(xr + 4 * i);
            c0 = fmaf(xv.x, wg0[i].x, fmaf(xv.y, wg0[i].y, fmaf(xv.z, wg0[i].z, fmaf(xv.w, wg0[i].w, c0))));
            c1 = fmaf(xv.x, wg1[i].x, fmaf(xv.y, wg1[i].y, fmaf(xv.z, wg1[i].z, fmaf(xv.w, wg1[i].w, c1))));
            n0 = fmaf(xv.x, wn0[i].x, fmaf(xv.y, wn0[i].y, fmaf(xv.z, wn0[i].z, fmaf(xv.w, wn0[i].w, n0))));
            n1 = fmaf(xv.x, wn1[i].x, fmaf(xv.y, wn1[i].y, fmaf(xv.z, wn1[i].z, fmaf(xv.w, wn1[i].w, n1))));
        }
        // 64-lane butterfly reduction (wavefront = 64 on gfx950)
#pragma unroll
        for (int off = 32; off; off >>= 1) {
            c0 += __shfl_xor(c0, off);
            c1 += __shfl_xor(c1, off);
            n0 += __shfl_xor(n0, off);
            n1 += __shfl_xor(n1, off);
        }
        if (lane == 0) {
            float std0 = softplusf(n0) + 0.01f;
            float std1 = softplusf(n1) + 0.01f;
            float2 nsr = *(const float2*)(ns + 2 * (size_t)row);
            float h0 = fmaf(nsr.x, std0, c0);
            float h1 = fmaf(nsr.y, std1, c1);
            // softmax over 2
            float m  = fmaxf(h0, h1);
            float e0 = expf(h0 - m);
            float e1 = expf(h1 - m);
            float inv = 1.0f / (e0 + e1);
            float l0 = e0 * inv;
            float l1 = e1 * inv;
            float ent = -(l0 * logf(l0 + 1e-10f) + l1 * logf(l1 + 1e-10f));
            // E=2 top-p: sorted via stable descending argsort (tie -> expert 0 first)
            bool  first = (l0 >= l1);
            float ps0 = first ? l0 : l1;   // max prob
            float ps1 = first ? l1 : l0;
            bool  toponly = ps0 > 0.7f;    // identical predicate to `cum > TOP_P`
            imp0 += (double)ps0;
            if (!toponly) imp1 += (double)ps1;
            entsum += (double)ent;
            float w0, w1;
            if (toponly) { w0 = first ? 1.f : 0.f; w1 = 1.f - w0; }
            else         { w0 = 1.f; w1 = 1.f; }
            *(float2*)(out + 2 * (size_t)row) = make_float2(w0, w1);
            out[OUT_DEC + row] = toponly ? 0.f : 1.f;
        }
    }
    if (lane == 0) {
        atomicAdd(&acc[0], imp0);
        atomicAdd(&acc[1], imp1);
        atomicAdd(&acc[2], entsum);
    }
}

__global__ void router_final(const double* __restrict__ acc,
                             float* __restrict__ out) {
    double a = acc[0], b = acc[1], ent = acc[2];
    double mean = 0.5 * (a + b);
    double var  = 0.5 * (a - b) * (a - b);   // ddof=1, E=2
    double li   = var / (mean * mean + 1e-10);
    double ld   = ent / (double)ROWS;
    out[OUT_LOSS] = (float)(li + 0.1 * ld);
}

extern "C" void kernel_launch(void* const* d_in, const int* in_sizes, int n_in,
                              void* d_out, int out_size, void* d_ws, size_t ws_size,
                              hipStream_t stream) {
    const float* x       = (const float*)d_in[0];
    const float* gate_w  = (const float*)d_in[1];
    const float* noise_w = (const float*)d_in[2];
    const float* ns      = (const float*)d_in[3];
    float*  out = (float*)d_out;
    double* acc = (double*)d_ws;

    hipMemsetAsync(d_ws, 0, 3 * sizeof(double), stream);
    // 1024 blocks x 256 threads = 4096 waves, 8 rows each; fully coalesced row reads.
    router_main<<<1024, 256, 0, stream>>>(x, gate_w, noise_w, ns, out, acc);
    router_final<<<1, 1, 0, stream>>>(acc, out);
}

// Round 2
// 38.108 us; speedup vs baseline: 4.6981x; 4.6981x over previous
//
#include <hip/hip_runtime.h>
#include <math.h>

// ExpertRouter: B=8, N=4096, D=1024, E=2  -> rows = 32768
// Outputs (concatenated float32):
//   [0 .. 65535]        expert_weights  [rows,2]  (0/1)
//   [65536 .. 98303]    expert_decisions [rows]   (0/1, "both experts kept")
//   [98304]             gating_loss scalar

constexpr int D = 1024;
constexpr int ROWS = 32768;
constexpr int OUT_DEC = ROWS * 2;   // 65536
constexpr int OUT_LOSS = ROWS * 3;  // 98304
constexpr int BLOCKS = 2048;        // 8192 waves, 4 rows each; 32 waves/CU

static __device__ __forceinline__ float softplusf(float v) {
    // logaddexp(v, 0) = max(v,0) + log1p(exp(-|v|))  (matches jax.nn.softplus)
    return fmaxf(v, 0.0f) + log1pf(expf(-fabsf(v)));
}

__global__ __launch_bounds__(256) void router_main(
    const float* __restrict__ x,        // [ROWS, D]
    const float* __restrict__ gate_w,   // [2, D]
    const float* __restrict__ noise_w,  // [2, D]
    const float* __restrict__ ns,       // [ROWS, 2]
    float* __restrict__ out,            // [ROWS*3 + 1]
    double* __restrict__ part)          // [BLOCKS*3] per-block partials
{
    const int lane   = threadIdx.x & 63;
    const int wid    = threadIdx.x >> 6;          // wave within block (0..3)
    const int gtid   = blockIdx.x * blockDim.x + threadIdx.x;
    const int wave   = gtid >> 6;
    const int nwaves = (gridDim.x * blockDim.x) >> 6;
    const int base   = lane * 16;   // 64 lanes * 16 floats = 1024 = D

    // Per-lane slice of all 4 weight rows (compiler may re-load from L1; fine).
    float4 wg0[4], wg1[4], wn0[4], wn1[4];
#pragma unroll
    for (int i = 0; i < 4; ++i) {
        wg0[i] = *(const float4*)(gate_w + base + 4 * i);
        wg1[i] = *(const float4*)(gate_w + D + base + 4 * i);
        wn0[i] = *(const float4*)(noise_w + base + 4 * i);
        wn1[i] = *(const float4*)(noise_w + D + base + 4 * i);
    }

    double imp0 = 0.0, imp1 = 0.0, entsum = 0.0;

    for (int row = wave; row < ROWS; row += nwaves) {
        // broadcast prefetch of this row's noise sample (same addr on all lanes)
        float2 nsr = *(const float2*)(ns + 2 * (size_t)row);
        const float* xr = x + (size_t)row * D + base;
        float c0 = 0.f, c1 = 0.f, n0 = 0.f, n1 = 0.f;
#pragma unroll
        for (int i = 0; i < 4; ++i) {
            float4 xv = *(const float4*)(xr + 4 * i);
            c0 = fmaf(xv.x, wg0[i].x, fmaf(xv.y, wg0[i].y, fmaf(xv.z, wg0[i].z, fmaf(xv.w, wg0[i].w, c0))));
            c1 = fmaf(xv.x, wg1[i].x, fmaf(xv.y, wg1[i].y, fmaf(xv.z, wg1[i].z, fmaf(xv.w, wg1[i].w, c1))));
            n0 = fmaf(xv.x, wn0[i].x, fmaf(xv.y, wn0[i].y, fmaf(xv.z, wn0[i].z, fmaf(xv.w, wn0[i].w, n0))));
            n1 = fmaf(xv.x, wn1[i].x, fmaf(xv.y, wn1[i].y, fmaf(xv.z, wn1[i].z, fmaf(xv.w, wn1[i].w, n1))));
        }
        // 64-lane butterfly reduction; result broadcast to ALL lanes
#pragma unroll
        for (int off = 32; off; off >>= 1) {
            c0 += __shfl_xor(c0, off);
            c1 += __shfl_xor(c1, off);
            n0 += __shfl_xor(n0, off);
            n1 += __shfl_xor(n1, off);
        }
        // Uniform epilogue on all lanes (no divergence); only stores predicated.
        float std0 = softplusf(n0) + 0.01f;
        float std1 = softplusf(n1) + 0.01f;
        float h0 = fmaf(nsr.x, std0, c0);
        float h1 = fmaf(nsr.y, std1, c1);
        float m  = fmaxf(h0, h1);
        float e0 = expf(h0 - m);
        float e1 = expf(h1 - m);
        float inv = 1.0f / (e0 + e1);
        float l0 = e0 * inv;
        float l1 = e1 * inv;
        float ent = -(l0 * logf(l0 + 1e-10f) + l1 * logf(l1 + 1e-10f));
        // E=2 top-p: stable descending argsort (tie -> expert 0 first)
        bool  first = (l0 >= l1);
        float ps0 = first ? l0 : l1;   // max prob
        float ps1 = first ? l1 : l0;
        bool  toponly = ps0 > 0.7f;    // identical predicate to `cum > TOP_P`
        imp0 += (double)ps0;
        if (!toponly) imp1 += (double)ps1;   // uniform across wave
        entsum += (double)ent;
        if (lane == 0) {
            float w0, w1;
            if (toponly) { w0 = first ? 1.f : 0.f; w1 = 1.f - w0; }
            else         { w0 = 1.f; w1 = 1.f; }
            *(float2*)(out + 2 * (size_t)row) = make_float2(w0, w1);
            out[OUT_DEC + row] = toponly ? 0.f : 1.f;
        }
    }

    // Block-level reduction of per-wave partials; ONE plain store per block.
    __shared__ double sred[4][3];
    if (lane == 0) {
        sred[wid][0] = imp0; sred[wid][1] = imp1; sred[wid][2] = entsum;
    }
    __syncthreads();
    if (threadIdx.x == 0) {
        double a = 0, b = 0, e = 0;
#pragma unroll
        for (int w = 0; w < 4; ++w) { a += sred[w][0]; b += sred[w][1]; e += sred[w][2]; }
        part[3 * (size_t)blockIdx.x + 0] = a;
        part[3 * (size_t)blockIdx.x + 1] = b;
        part[3 * (size_t)blockIdx.x + 2] = e;
    }
}

__global__ __launch_bounds__(256) void router_final(const double* __restrict__ part,
                                                    float* __restrict__ out) {
    const int lane = threadIdx.x & 63;
    const int wid  = threadIdx.x >> 6;
    double s0 = 0, s1 = 0, s2 = 0;
    for (int i = threadIdx.x; i < BLOCKS; i += 256) {
        s0 += part[3 * i + 0];
        s1 += part[3 * i + 1];
        s2 += part[3 * i + 2];
    }
#pragma unroll
    for (int off = 32; off; off >>= 1) {
        s0 += __shfl_xor(s0, off);
        s1 += __shfl_xor(s1, off);
        s2 += __shfl_xor(s2, off);
    }
    __shared__ double sl[4][3];
    if (lane == 0) { sl[wid][0] = s0; sl[wid][1] = s1; sl[wid][2] = s2; }
    __syncthreads();
    if (threadIdx.x == 0) {
        double a = 0, b = 0, ent = 0;
#pragma unroll
        for (int w = 0; w < 4; ++w) { a += sl[w][0]; b += sl[w][1]; ent += sl[w][2]; }
        double mean = 0.5 * (a + b);
        double var  = 0.5 * (a - b) * (a - b);   // ddof=1, E=2
        double li   = var / (mean * mean + 1e-10);
        double ld   = ent / (double)ROWS;
        out[OUT_LOSS] = (float)(li + 0.1 * ld);
    }
}

extern "C" void kernel_launch(void* const* d_in, const int* in_sizes, int n_in,
                              void* d_out, int out_size, void* d_ws, size_t ws_size,
                              hipStream_t stream) {
    const float* x       = (const float*)d_in[0];
    const float* gate_w  = (const float*)d_in[1];
    const float* noise_w = (const float*)d_in[2];
    const float* ns      = (const float*)d_in[3];
    float*  out  = (float*)d_out;
    double* part = (double*)d_ws;   // BLOCKS*3 doubles = 48 KiB

    router_main<<<BLOCKS, 256, 0, stream>>>(x, gate_w, noise_w, ns, out, part);
    router_final<<<1, 256, 0, stream>>>(part, out);
}